// Round 1
// baseline (363.065 us; speedup 1.0000x reference)
//
#include <hip/hip_runtime.h>
#include <math.h>

#define NB 2
#define NS 2048
#define ND 1024
#define NH 16
#define NHD 64

typedef __attribute__((ext_vector_type(4))) _Float16 f16x4;
typedef __attribute__((ext_vector_type(4))) float f32x4;

// C[M,N] = A[M,K] @ W[K,N].  A is fp32 or fp16 (A_F16), W fp32.
// OUT_MODE 0: write fp16 split-head layout [B,H,S,HD]; OUT_MODE 1: fp32 row-major [M,N].
template<bool A_F16, int OUT_MODE>
__global__ __launch_bounds__(256) void gemm_kernel(const void* __restrict__ Aptr,
                                                   const float* __restrict__ W,
                                                   void* __restrict__ Cptr,
                                                   int M, int N, int K) {
  __shared__ _Float16 As[64][20];   // 64 x 16 tile, +4 pad
  __shared__ _Float16 Bs[16][68];   // 16 x 64 tile, +4 pad

  const int ntn = N >> 6;
  const int bm = (blockIdx.x / ntn) << 6;
  const int bn = (blockIdx.x % ntn) << 6;
  const int tid  = threadIdx.x;
  const int lane = tid & 63;
  const int wave = tid >> 6;
  const int i16 = lane & 15;
  const int g4  = lane >> 4;
  const int wr = wave >> 1;   // 0..1  (32-row half)
  const int wc = wave & 1;    // 0..1  (32-col half)

  f32x4 acc[2][2] = {};

  const int ar = tid >> 2;          // 0..63
  const int ac = (tid & 3) << 2;    // 0,4,8,12
  const int br = tid >> 4;          // 0..15
  const int bc = (tid & 15) << 2;   // 0..60

  const int nkt = K >> 4;
  for (int kt = 0; kt < nkt; ++kt) {
    // ---- stage A tile (64x16) as fp16 ----
    if (A_F16) {
      const _Float16* A = (const _Float16*)Aptr;
      f16x4 v = *(const f16x4*)(A + (size_t)(bm + ar) * K + (kt << 4) + ac);
      *(f16x4*)&As[ar][ac] = v;
    } else {
      const float* A = (const float*)Aptr;
      float4 v = *(const float4*)(A + (size_t)(bm + ar) * K + (kt << 4) + ac);
      f16x4 hv = {(_Float16)v.x, (_Float16)v.y, (_Float16)v.z, (_Float16)v.w};
      *(f16x4*)&As[ar][ac] = hv;
    }
    // ---- stage B tile (16x64) as fp16 ----
    {
      float4 v = *(const float4*)(W + (size_t)((kt << 4) + br) * N + bn + bc);
      f16x4 hv = {(_Float16)v.x, (_Float16)v.y, (_Float16)v.z, (_Float16)v.w};
      *(f16x4*)&Bs[br][bc] = hv;
    }
    __syncthreads();

    f16x4 af[2], bf[2];
#pragma unroll
    for (int p = 0; p < 2; ++p)
      af[p] = *(const f16x4*)&As[(wr << 5) + (p << 4) + i16][g4 << 2];
#pragma unroll
    for (int p = 0; p < 2; ++p) {
      f16x4 t;
#pragma unroll
      for (int j = 0; j < 4; ++j)
        t[j] = Bs[(g4 << 2) + j][(wc << 5) + (p << 4) + i16];
      bf[p] = t;
    }
#pragma unroll
    for (int pa = 0; pa < 2; ++pa)
#pragma unroll
      for (int pb = 0; pb < 2; ++pb)
        acc[pa][pb] = __builtin_amdgcn_mfma_f32_16x16x16f16(af[pa], bf[pb], acc[pa][pb], 0, 0, 0);
    __syncthreads();
  }

  // ---- epilogue:  D[row=4*g4+j][col=i16] per 16x16 fragment ----
#pragma unroll
  for (int pa = 0; pa < 2; ++pa)
#pragma unroll
    for (int pb = 0; pb < 2; ++pb)
#pragma unroll
      for (int j = 0; j < 4; ++j) {
        const int row = bm + (wr << 5) + (pa << 4) + (g4 << 2) + j;
        const int col = bn + (wc << 5) + (pb << 4) + i16;
        const float val = acc[pa][pb][j];
        if (OUT_MODE == 0) {
          const int bb = row >> 11;          // row = b*NS + s
          const int ss = row & (NS - 1);
          const int hh = col >> 6;           // col = h*NHD + d
          const int dd = col & (NHD - 1);
          ((_Float16*)Cptr)[(((size_t)(bb * NH + hh) * NS + ss) << 6) + dd] = (_Float16)val;
        } else {
          ((float*)Cptr)[(size_t)row * N + col] = val;
        }
      }
}

// Flash attention over fp16 heads.  Grid: B*H*(S/64) blocks, 4 waves each.
// Each wave owns 16 query rows; online softmax over KV tiles of 64.
__global__ __launch_bounds__(256) void attn_kernel(const _Float16* __restrict__ Qh,
                                                   const _Float16* __restrict__ Kh,
                                                   const _Float16* __restrict__ Vh,
                                                   const int* __restrict__ valid_lens,
                                                   _Float16* __restrict__ ctx) {
  __shared__ _Float16 Ks[64][68];
  __shared__ _Float16 Vs[64][68];
  __shared__ _Float16 Ps[64][68];

  const int nqt = NS >> 6;               // 32
  const int bh = blockIdx.x / nqt;       // 0..B*H-1
  const int qt = blockIdx.x % nqt;
  const int b = bh >> 4;
  const int h = bh & 15;
  const int valid = valid_lens[b];
  const int tid  = threadIdx.x;
  const int lane = tid & 63;
  const int w   = tid >> 6;              // wave 0..3
  const int i16 = lane & 15;
  const int g4  = lane >> 4;

  const _Float16* Qb = Qh + ((size_t)bh * NS + (qt << 6)) * NHD;
  const _Float16* Kb = Kh + (size_t)bh * NS * NHD;
  const _Float16* Vb = Vh + (size_t)bh * NS * NHD;

  // Q fragments: wave w covers q rows [16w, 16w+16); A-frag row = i16, k = 4*g4+j
  f16x4 qf[4];
#pragma unroll
  for (int dc = 0; dc < 4; ++dc)
    qf[dc] = *(const f16x4*)(Qb + (size_t)((w << 4) + i16) * NHD + (dc << 4) + (g4 << 2));

  f32x4 acc[4] = {};                      // ctx accum, d-chunks of 16
  float mrow[4] = {-1e30f, -1e30f, -1e30f, -1e30f};
  float lsum[4] = {0.f, 0.f, 0.f, 0.f};

  const int sr = tid >> 2;                // 0..63
  const int sc = (tid & 3) << 4;          // 0,16,32,48

  const int ntiles = (valid + 63) >> 6;
  for (int t = 0; t < ntiles; ++t) {
    __syncthreads();                      // prev-iter reads done before restage
    {
      const f16x4* srcK = (const f16x4*)(Kb + (size_t)((t << 6) + sr) * NHD + sc);
      const f16x4* srcV = (const f16x4*)(Vb + (size_t)((t << 6) + sr) * NHD + sc);
#pragma unroll
      for (int u = 0; u < 4; ++u) {
        *(f16x4*)&Ks[sr][sc + (u << 2)] = srcK[u];
        *(f16x4*)&Vs[sr][sc + (u << 2)] = srcV[u];
      }
    }
    __syncthreads();

    // scores: S[q][kv] = Q·K^T / 8, masked
    float pj[4][4];                       // [cf][j]
#pragma unroll
    for (int cf = 0; cf < 4; ++cf) {
      f32x4 sa = {};
#pragma unroll
      for (int dc = 0; dc < 4; ++dc) {
        f16x4 kf = *(const f16x4*)&Ks[(cf << 4) + i16][(dc << 4) + (g4 << 2)];
        sa = __builtin_amdgcn_mfma_f32_16x16x16f16(qf[dc], kf, sa, 0, 0, 0);
      }
      const int kvcol = (t << 6) + (cf << 4) + i16;
#pragma unroll
      for (int j = 0; j < 4; ++j) {
        const float s = sa[j] * 0.125f;
        pj[cf][j] = (kvcol >= valid) ? -1000000.0f : s;
      }
    }

    // row-wise online softmax (rows = 4*g4+j of this wave's 16)
    float tmax[4];
#pragma unroll
    for (int j = 0; j < 4; ++j)
      tmax[j] = fmaxf(fmaxf(pj[0][j], pj[1][j]), fmaxf(pj[2][j], pj[3][j]));
    for (int off = 1; off < 16; off <<= 1)
#pragma unroll
      for (int j = 0; j < 4; ++j)
        tmax[j] = fmaxf(tmax[j], __shfl_xor(tmax[j], off, 64));

    float rowsum[4] = {0.f, 0.f, 0.f, 0.f};
#pragma unroll
    for (int j = 0; j < 4; ++j) {
      const float mn = fmaxf(mrow[j], tmax[j]);
      const float scv = expf(mrow[j] - mn);   // 0 on first tile
      mrow[j] = mn;
      lsum[j] *= scv;
#pragma unroll
      for (int dn = 0; dn < 4; ++dn) acc[dn][j] *= scv;
    }
#pragma unroll
    for (int cf = 0; cf < 4; ++cf)
#pragma unroll
      for (int j = 0; j < 4; ++j) {
        const float p = expf(pj[cf][j] - mrow[j]);  // masked -> exactly 0
        rowsum[j] += p;
        Ps[(w << 4) + (g4 << 2) + j][(cf << 4) + i16] = (_Float16)p;
      }
    for (int off = 1; off < 16; off <<= 1)
#pragma unroll
      for (int j = 0; j < 4; ++j)
        rowsum[j] += __shfl_xor(rowsum[j], off, 64);
#pragma unroll
    for (int j = 0; j < 4; ++j) lsum[j] += rowsum[j];

    __syncthreads();                      // P visible (and ordered) before PV

    // PV: ctx += P @ V
#pragma unroll
    for (int cf = 0; cf < 4; ++cf) {
      f16x4 pf = *(const f16x4*)&Ps[(w << 4) + i16][(cf << 4) + (g4 << 2)];
#pragma unroll
      for (int dn = 0; dn < 4; ++dn) {
        f16x4 vf;
#pragma unroll
        for (int j = 0; j < 4; ++j)
          vf[j] = Vs[(cf << 4) + (g4 << 2) + j][(dn << 4) + i16];
        acc[dn] = __builtin_amdgcn_mfma_f32_16x16x16f16(pf, vf, acc[dn], 0, 0, 0);
      }
    }
  }

  // epilogue: ctx[b][q][h*64+d] = acc / lsum, fp16
#pragma unroll
  for (int dn = 0; dn < 4; ++dn)
#pragma unroll
    for (int j = 0; j < 4; ++j) {
      const int q = (qt << 6) + (w << 4) + (g4 << 2) + j;
      const int d = (h << 6) + (dn << 4) + i16;
      ctx[((size_t)b * NS + q) * ND + d] = (_Float16)(acc[dn][j] / lsum[j]);
    }
}

extern "C" void kernel_launch(void* const* d_in, const int* in_sizes, int n_in,
                              void* d_out, int out_size, void* d_ws, size_t ws_size,
                              hipStream_t stream) {
  const float* q  = (const float*)d_in[0];
  const float* k  = (const float*)d_in[1];
  const float* v  = (const float*)d_in[2];
  const int*   vl = (const int*)d_in[3];
  const float* Wq = (const float*)d_in[4];
  const float* Wk = (const float*)d_in[5];
  const float* Wv = (const float*)d_in[6];
  const float* Wo = (const float*)d_in[7];
  float* out = (float*)d_out;

  const size_t elems = (size_t)NB * NS * ND;   // 4M
  _Float16* Qh = (_Float16*)d_ws;
  _Float16* Kh = Qh + elems;
  _Float16* Vh = Kh + elems;
  _Float16* cx = Vh + elems;                    // ctx fp16 [B,S,D]

  const int M = NB * NS;                        // 4096
  dim3 blk(256);
  dim3 gproj((M >> 6) * (ND >> 6));             // 1024 blocks

  gemm_kernel<false, 0><<<gproj, blk, 0, stream>>>(q, Wq, Qh, M, ND, ND);
  gemm_kernel<false, 0><<<gproj, blk, 0, stream>>>(k, Wk, Kh, M, ND, ND);
  gemm_kernel<false, 0><<<gproj, blk, 0, stream>>>(v, Wv, Vh, M, ND, ND);
  attn_kernel<<<dim3(NB * NH * (NS >> 6)), blk, 0, stream>>>(Qh, Kh, Vh, vl, cx);
  gemm_kernel<true, 1><<<gproj, blk, 0, stream>>>(cx, Wo, out, M, ND, ND);
}

// Round 2
// 249.618 us; speedup vs baseline: 1.4545x; 1.4545x over previous
//
#include <hip/hip_runtime.h>
#include <math.h>

#define NB 2
#define NS 2048
#define ND 1024
#define NH 16
#define NHD 64
#define GK 1024
#define NEG -1000000.0f

typedef __attribute__((ext_vector_type(4))) float f32x4;
typedef __attribute__((ext_vector_type(8))) _Float16 f16x8;
typedef __attribute__((ext_vector_type(4))) _Float16 f16x4;

typedef const __attribute__((address_space(1))) unsigned int* gas_t;
typedef __attribute__((address_space(3))) unsigned int* las_t;

// ---------- fused convert+transpose: W fp32 [K][N] -> Wt fp16 [N][K], x4 ----------
__global__ __launch_bounds__(256) void wt_kernel(const float* __restrict__ Wq,
                                                 const float* __restrict__ Wk,
                                                 const float* __restrict__ Wv,
                                                 const float* __restrict__ Wo,
                                                 _Float16* __restrict__ WtBase) {
  __shared__ _Float16 Ts[64][72];
  const int which = blockIdx.x >> 8;
  const int rem = blockIdx.x & 255;
  const int tk = rem >> 4;
  const int tn = rem & 15;
  const float* W = which == 0 ? Wq : which == 1 ? Wk : which == 2 ? Wv : Wo;
  _Float16* Wt = WtBase + (size_t)which * (GK * ND);
  const int t = threadIdx.x;
#pragma unroll
  for (int p = 0; p < 4; ++p) {
    const int kr = (p << 4) + (t >> 4);
    const int nc = (t & 15) << 2;
    float4 v = *(const float4*)(W + (size_t)((tk << 6) + kr) * ND + (tn << 6) + nc);
    f16x4 h = {(_Float16)v.x, (_Float16)v.y, (_Float16)v.z, (_Float16)v.w};
    *(f16x4*)&Ts[kr][nc] = h;
  }
  __syncthreads();
#pragma unroll
  for (int p = 0; p < 4; ++p) {
    const int nr = (p << 4) + (t >> 4);
    const int kc = (t & 15) << 2;
    f16x4 h;
#pragma unroll
    for (int u = 0; u < 4; ++u) h[u] = Ts[kc + u][nr];
    *(f16x4*)(Wt + (size_t)((tn << 6) + nr) * GK + (tk << 6) + kc) = h;
  }
}

// ---------- 128-tile MFMA GEMM ----------
// AMODE 0: A fp32 row-major [M][K].  AMODE 1: A fp16 split-head [B,H,S,HD].
// OMODE 0: out fp16 split-head (base + which*4M).  OMODE 1: out fp32 row-major.
// BN: 128 (proj, fused x3 via which=blockIdx/BLKS) or 64.
template<int AMODE, int OMODE, int BN>
__global__ __launch_bounds__(256) void gemm_kernel(const void* __restrict__ Ap0,
                                                   const void* __restrict__ Ap1,
                                                   const void* __restrict__ Ap2,
                                                   const _Float16* __restrict__ BtBase,
                                                   void* __restrict__ OutBase) {
  constexpr int BM = 128, BK = 32;
  constexpr int NBN = ND / BN;
  constexpr int BLKS = (NB * NS / BM) * NBN;
  constexpr int NF = BN / 32;
  __shared__ float    As32[AMODE == 0 ? BM * BK : 8];
  __shared__ _Float16 As16[AMODE == 1 ? BM * BK : 8];
  __shared__ _Float16 Bs[BN * BK];

  int idx = blockIdx.x;
  const int which = idx / BLKS;
  idx -= which * BLKS;
  const int bm = (idx / NBN) * BM;
  const int bn = (idx % NBN) * BN;
  const void* Ap = which == 0 ? Ap0 : which == 1 ? Ap1 : Ap2;
  const _Float16* Bt = BtBase + (size_t)which * (ND * GK);

  const int tid = threadIdx.x, lane = tid & 63, w = tid >> 6;
  const int i16 = lane & 15, g4 = lane >> 4;
  const int wr = w >> 1, wc = w & 1;

  f32x4 acc[4][NF] = {};

  for (int kt = 0; kt < GK / BK; ++kt) {
    // ---- stage A (global_load_lds, pre-swizzled source) ----
    if (AMODE == 0) {
      const float* A = (const float*)Ap;
#pragma unroll
      for (int u = 0; u < 4; ++u) {
        const int chunk = (((w << 2) + u) << 6) + lane;   // 0..1023, 16B each
        const int r = chunk >> 3;
        const int c = (chunk & 7) ^ (r & 7);
        __builtin_amdgcn_global_load_lds(
            (gas_t)(const void*)(A + (size_t)(bm + r) * GK + (kt << 5) + (c << 2)),
            (las_t)(void*)&As32[((w << 2) + u) << 8], 16, 0, 0);
      }
    } else {
      const _Float16* A = (const _Float16*)Ap;
#pragma unroll
      for (int u = 0; u < 2; ++u) {
        const int chunk = (((w << 1) + u) << 6) + lane;   // 0..511
        const int r = chunk >> 2;
        const int c = (chunk & 3) ^ (r & 3);
        const int m = bm + r;
        const int kcol = (kt << 5) + (c << 3);
        const int bb = m >> 11, ss = m & (NS - 1);
        const int hh = kcol >> 6, dd = kcol & 63;
        __builtin_amdgcn_global_load_lds(
            (gas_t)(const void*)(A + (((size_t)(bb * NH + hh) * NS + ss) << 6) + dd),
            (las_t)(void*)&As16[((w << 1) + u) << 9], 16, 0, 0);
      }
    }
    // ---- stage B ----
    {
      constexpr int CPT = (BN * BK * 2 / 16) / 256;  // chunks per thread (2 or 1)
#pragma unroll
      for (int u = 0; u < CPT; ++u) {
        const int chunk = ((w * CPT + u) << 6) + lane;
        const int r = chunk >> 2;
        const int c = (chunk & 3) ^ (r & 3);
        __builtin_amdgcn_global_load_lds(
            (gas_t)(const void*)(Bt + (size_t)(bn + r) * GK + (kt << 5) + (c << 3)),
            (las_t)(void*)&Bs[(w * CPT + u) << 9], 16, 0, 0);
      }
    }
    __syncthreads();

    f16x8 af[4], bf[NF];
#pragma unroll
    for (int mi = 0; mi < 4; ++mi) {
      const int r = (wr << 6) + (mi << 4) + i16;
      if (AMODE == 0) {
        const f32x4 v0 = *(const f32x4*)&As32[(r << 5) + ((((g4 << 1) | 0) ^ (r & 7)) << 2)];
        const f32x4 v1 = *(const f32x4*)&As32[(r << 5) + ((((g4 << 1) | 1) ^ (r & 7)) << 2)];
        f16x8 h;
#pragma unroll
        for (int j = 0; j < 4; ++j) { h[j] = (_Float16)v0[j]; h[4 + j] = (_Float16)v1[j]; }
        af[mi] = h;
      } else {
        af[mi] = *(const f16x8*)&As16[(r << 5) + ((g4 ^ (r & 3)) << 3)];
      }
    }
#pragma unroll
    for (int ni = 0; ni < NF; ++ni) {
      const int r = wc * (BN / 2) + (ni << 4) + i16;
      bf[ni] = *(const f16x8*)&Bs[(r << 5) + ((g4 ^ (r & 3)) << 3)];
    }
#pragma unroll
    for (int mi = 0; mi < 4; ++mi)
#pragma unroll
      for (int ni = 0; ni < NF; ++ni)
        acc[mi][ni] = __builtin_amdgcn_mfma_f32_16x16x32_f16(af[mi], bf[ni], acc[mi][ni], 0, 0, 0);
    __syncthreads();
  }

  // ---- epilogue ----
#pragma unroll
  for (int mi = 0; mi < 4; ++mi)
#pragma unroll
    for (int ni = 0; ni < NF; ++ni)
#pragma unroll
      for (int j = 0; j < 4; ++j) {
        const int row = bm + (wr << 6) + (mi << 4) + (g4 << 2) + j;
        const int col = bn + wc * (BN / 2) + (ni << 4) + i16;
        const float val = acc[mi][ni][j];
        if (OMODE == 0) {
          const int bb = row >> 11, ss = row & (NS - 1);
          const int hh = col >> 6, dd = col & 63;
          _Float16* Out = (_Float16*)OutBase + (size_t)which * ((size_t)NB * NS * ND);
          Out[(((size_t)(bb * NH + hh) * NS + ss) << 6) + dd] = (_Float16)val;
        } else {
          ((float*)OutBase)[(size_t)row * ND + col] = val;
        }
      }
}

// ---------- flash attention, 16x16x32 MFMA, ctx written in place over Qh ----------
__global__ __launch_bounds__(256) void attn_kernel(_Float16* __restrict__ Qc,
                                                   const _Float16* __restrict__ Kh,
                                                   const _Float16* __restrict__ Vh,
                                                   const int* __restrict__ valid_lens) {
  __shared__ _Float16 Ks[64][72];
  __shared__ _Float16 Vt[64][72];
  __shared__ _Float16 Ps[64][72];

  const int nqt = NS >> 6;
  const int bh = blockIdx.x / nqt;
  const int qt = blockIdx.x % nqt;
  const int b = bh >> 4;
  const int valid = valid_lens[b];
  const int tid = threadIdx.x, lane = tid & 63, w = tid >> 6;
  const int i16 = lane & 15, g4 = lane >> 4;

  _Float16* Qb = Qc + ((size_t)bh * NS + (qt << 6)) * NHD;
  const _Float16* Kb = Kh + (size_t)bh * NS * NHD;
  const _Float16* Vb = Vh + (size_t)bh * NS * NHD;

  f16x8 qf[2];
#pragma unroll
  for (int dc = 0; dc < 2; ++dc)
    qf[dc] = *(const f16x8*)(Qb + (size_t)((w << 4) + i16) * NHD + (dc << 5) + (g4 << 3));

  f32x4 acc[4] = {};
  float mrow[4] = {-1e30f, -1e30f, -1e30f, -1e30f};
  float lsum[4] = {0.f, 0.f, 0.f, 0.f};

  const int ntiles = (valid + 63) >> 6;
  for (int t = 0; t < ntiles; ++t) {
    __syncthreads();                       // prev-tile LDS reads done
    // stage K row-major (vector copies, padded rows)
#pragma unroll
    for (int u = 0; u < 2; ++u) {
      const int chunk = (u << 8) + tid;    // 0..511
      const int r = chunk >> 3, c8 = (chunk & 7) << 3;
      *(f16x8*)&Ks[r][c8] = *(const f16x8*)(Kb + (size_t)((t << 6) + r) * NHD + c8);
    }
    // stage V transposed: Vt[d][kv]
    {
      const int kv = tid >> 2;
      const int db = (tid & 3) << 4;
#pragma unroll
      for (int u = 0; u < 4; ++u) {
        f16x4 vv = *(const f16x4*)(Vb + (size_t)((t << 6) + kv) * NHD + db + (u << 2));
#pragma unroll
        for (int e = 0; e < 4; ++e) Vt[db + (u << 2) + e][kv] = vv[e];
      }
    }
    __syncthreads();

    // QK^T
    float pj[4][4];
#pragma unroll
    for (int cf = 0; cf < 4; ++cf) {
      f32x4 sa = {};
#pragma unroll
      for (int dc = 0; dc < 2; ++dc) {
        f16x8 kf = *(const f16x8*)&Ks[(cf << 4) + i16][(dc << 5) + (g4 << 3)];
        sa = __builtin_amdgcn_mfma_f32_16x16x32_f16(qf[dc], kf, sa, 0, 0, 0);
      }
      const int kvcol = (t << 6) + (cf << 4) + i16;
#pragma unroll
      for (int j = 0; j < 4; ++j)
        pj[cf][j] = (kvcol >= valid) ? NEG : sa[j] * 0.125f;
    }

    // online softmax (rows = w*16 + 4*g4 + j)
    float tmax[4];
#pragma unroll
    for (int j = 0; j < 4; ++j)
      tmax[j] = fmaxf(fmaxf(pj[0][j], pj[1][j]), fmaxf(pj[2][j], pj[3][j]));
    for (int off = 1; off < 16; off <<= 1)
#pragma unroll
      for (int j = 0; j < 4; ++j)
        tmax[j] = fmaxf(tmax[j], __shfl_xor(tmax[j], off, 64));

    float rowsum[4] = {0.f, 0.f, 0.f, 0.f};
#pragma unroll
    for (int j = 0; j < 4; ++j) {
      const float mn = fmaxf(mrow[j], tmax[j]);
      const float scv = __expf(mrow[j] - mn);
      mrow[j] = mn;
      lsum[j] *= scv;
#pragma unroll
      for (int dn = 0; dn < 4; ++dn) acc[dn][j] *= scv;
    }
#pragma unroll
    for (int cf = 0; cf < 4; ++cf)
#pragma unroll
      for (int j = 0; j < 4; ++j) {
        const float p = __expf(pj[cf][j] - mrow[j]);
        rowsum[j] += p;
        Ps[(w << 4) + (g4 << 2) + j][(cf << 4) + i16] = (_Float16)p;
      }
    for (int off = 1; off < 16; off <<= 1)
#pragma unroll
      for (int j = 0; j < 4; ++j)
        rowsum[j] += __shfl_xor(rowsum[j], off, 64);
#pragma unroll
    for (int j = 0; j < 4; ++j) lsum[j] += rowsum[j];

    // PV (P rows are own-wave; no barrier needed — compiler orders LDS ops)
#pragma unroll
    for (int ks = 0; ks < 2; ++ks) {
      f16x8 pf = *(const f16x8*)&Ps[(w << 4) + i16][(ks << 5) + (g4 << 3)];
#pragma unroll
      for (int dn = 0; dn < 4; ++dn) {
        f16x8 vf = *(const f16x8*)&Vt[(dn << 4) + i16][(ks << 5) + (g4 << 3)];
        acc[dn] = __builtin_amdgcn_mfma_f32_16x16x32_f16(pf, vf, acc[dn], 0, 0, 0);
      }
    }
  }

  // epilogue: ctx overwrites this block's own Q rows (same split-head layout)
#pragma unroll
  for (int dn = 0; dn < 4; ++dn)
#pragma unroll
    for (int j = 0; j < 4; ++j) {
      const int qrow = (w << 4) + (g4 << 2) + j;
      Qb[(size_t)qrow * NHD + (dn << 4) + i16] = (_Float16)(acc[dn][j] / lsum[j]);
    }
}

extern "C" void kernel_launch(void* const* d_in, const int* in_sizes, int n_in,
                              void* d_out, int out_size, void* d_ws, size_t ws_size,
                              hipStream_t stream) {
  const float* q  = (const float*)d_in[0];
  const float* k  = (const float*)d_in[1];
  const float* v  = (const float*)d_in[2];
  const int*   vl = (const int*)d_in[3];
  const float* Wq = (const float*)d_in[4];
  const float* Wk = (const float*)d_in[5];
  const float* Wv = (const float*)d_in[6];
  const float* Wo = (const float*)d_in[7];

  _Float16* ws = (_Float16*)d_ws;
  _Float16* Qh = ws;                         // 4M f16 (becomes ctx in place)
  _Float16* Kh = ws + 4194304;
  _Float16* Vh = ws + 8388608;
  _Float16* Wt = ws + 12582912;              // 4 x 1M f16 (q,k,v,o transposed)

  wt_kernel<<<dim3(1024), dim3(256), 0, stream>>>(Wq, Wk, Wv, Wo, Wt);
  gemm_kernel<0, 0, 128><<<dim3(768), dim3(256), 0, stream>>>(q, k, v, Wt, Qh);
  attn_kernel<<<dim3(NB * NH * (NS >> 6)), dim3(256), 0, stream>>>(Qh, Kh, Vh, vl);
  gemm_kernel<1, 1, 64><<<dim3(512), dim3(256), 0, stream>>>(Qh, Qh, Qh, Wt + 3145728, d_out);
}

// Round 3
// 226.138 us; speedup vs baseline: 1.6055x; 1.1038x over previous
//
#include <hip/hip_runtime.h>
#include <math.h>

#define NB 2
#define NS 2048
#define ND 1024
#define NH 16
#define NHD 64
#define GK 1024
#define NEG -1000000.0f

typedef __attribute__((ext_vector_type(4))) float f32x4;
typedef __attribute__((ext_vector_type(8))) _Float16 f16x8;
typedef __attribute__((ext_vector_type(4))) _Float16 f16x4;

typedef const __attribute__((address_space(1))) unsigned int* gas_t;
typedef __attribute__((address_space(3))) unsigned int* las_t;

// ---------- fused convert+transpose: W fp32 [K][N] -> Wt fp16 [N][K], x4 ----------
__global__ __launch_bounds__(256) void wt_kernel(const float* __restrict__ Wq,
                                                 const float* __restrict__ Wk,
                                                 const float* __restrict__ Wv,
                                                 const float* __restrict__ Wo,
                                                 _Float16* __restrict__ WtBase) {
  __shared__ _Float16 Ts[64][72];
  const int which = blockIdx.x >> 8;
  const int rem = blockIdx.x & 255;
  const int tk = rem >> 4;
  const int tn = rem & 15;
  const float* W = which == 0 ? Wq : which == 1 ? Wk : which == 2 ? Wv : Wo;
  _Float16* Wt = WtBase + (size_t)which * (GK * ND);
  const int t = threadIdx.x;
#pragma unroll
  for (int p = 0; p < 4; ++p) {
    const int kr = (p << 4) + (t >> 4);
    const int nc = (t & 15) << 2;
    float4 v = *(const float4*)(W + (size_t)((tk << 6) + kr) * ND + (tn << 6) + nc);
    f16x4 h = {(_Float16)v.x, (_Float16)v.y, (_Float16)v.z, (_Float16)v.w};
    *(f16x4*)&Ts[kr][nc] = h;
  }
  __syncthreads();
#pragma unroll
  for (int p = 0; p < 4; ++p) {
    const int nr = (p << 4) + (t >> 4);
    const int kc = (t & 15) << 2;
    f16x4 h;
#pragma unroll
    for (int u = 0; u < 4; ++u) h[u] = Ts[kc + u][nr];
    *(f16x4*)(Wt + (size_t)((tn << 6) + nr) * GK + (tk << 6) + kc) = h;
  }
}

// ---------- fused Q/K/V projection GEMM: x(fp32) @ Wt^T -> Qh(x0.125)/Kh split-head, VhT transposed ----------
__global__ __launch_bounds__(256) void proj_kernel(const float* __restrict__ xq,
                                                   const float* __restrict__ xk,
                                                   const float* __restrict__ xv,
                                                   const _Float16* __restrict__ WtBase,
                                                   _Float16* __restrict__ Qh,
                                                   _Float16* __restrict__ Kh,
                                                   _Float16* __restrict__ VhT) {
  constexpr int BK = 32;
  __shared__ alignas(16) _Float16 As[128 * BK];
  __shared__ alignas(16) _Float16 Bs[128 * BK];

  // XCD-aware bijective remap: all 8 n-tiles of one (which, mt) panel -> same XCD
  int idx = ((blockIdx.x % 96) << 3) + (blockIdx.x / 96);
  const int which = idx >> 8;
  idx &= 255;
  const int bm = (idx >> 3) << 7;
  const int bn = (idx & 7) << 7;
  const float* A = which == 0 ? xq : which == 1 ? xk : xv;
  const _Float16* Bt = WtBase + (size_t)which * (ND * GK);

  const int tid = threadIdx.x, lane = tid & 63, w = tid >> 6;
  const int i16 = lane & 15, g4 = lane >> 4;
  const int wr = w >> 1, wc = w & 1;

  f32x4 acc[4][4] = {};

  for (int kt = 0; kt < GK / BK; ++kt) {
    // ---- stage A: fp32 load -> cvt fp16 -> ds_write_b128 (swizzled slots) ----
#pragma unroll
    for (int u = 0; u < 2; ++u) {
      const int c = (((w << 1) + u) << 6) + lane;   // 0..511
      const int r = c >> 2, sl = c & 3;
      const float* src = A + (size_t)(bm + r) * GK + (kt << 5) + ((sl ^ (r & 3)) << 3);
      float4 v0 = *(const float4*)src;
      float4 v1 = *(const float4*)(src + 4);
      f16x8 h;
#pragma unroll
      for (int j = 0; j < 4; ++j) { h[j] = (_Float16)v0[j]; h[4 + j] = (_Float16)v1[j]; }
      *(f16x8*)&As[(r << 5) + (sl << 3)] = h;
    }
    // ---- stage B via global_load_lds ----
#pragma unroll
    for (int u = 0; u < 2; ++u) {
      const int cb = ((w << 1) + u) << 6;
      const int c = cb + lane;
      const int r = c >> 2, sl = c & 3;
      __builtin_amdgcn_global_load_lds(
          (gas_t)(const void*)(Bt + (size_t)(bn + r) * GK + (kt << 5) + ((sl ^ (r & 3)) << 3)),
          (las_t)(void*)&Bs[cb << 3], 16, 0, 0);
    }
    __syncthreads();

    f16x8 af[4], bf[4];
#pragma unroll
    for (int mi = 0; mi < 4; ++mi) {
      const int r = (wr << 6) + (mi << 4) + i16;
      af[mi] = *(const f16x8*)&As[(r << 5) + ((g4 ^ (r & 3)) << 3)];
    }
#pragma unroll
    for (int ni = 0; ni < 4; ++ni) {
      const int r = (wc << 6) + (ni << 4) + i16;
      bf[ni] = *(const f16x8*)&Bs[(r << 5) + ((g4 ^ (r & 3)) << 3)];
    }
#pragma unroll
    for (int mi = 0; mi < 4; ++mi)
#pragma unroll
      for (int ni = 0; ni < 4; ++ni)
        acc[mi][ni] = __builtin_amdgcn_mfma_f32_16x16x32_f16(af[mi], bf[ni], acc[mi][ni], 0, 0, 0);
    __syncthreads();
  }

  // ---- epilogue ----
  if (which == 2) {
    // V: write transposed VhT[b,h,d,s]; acc j-elems are 4 consecutive rows (s) -> f16x4
#pragma unroll
    for (int mi = 0; mi < 4; ++mi)
#pragma unroll
      for (int ni = 0; ni < 4; ++ni) {
        const int row0 = bm + (wr << 6) + (mi << 4) + (g4 << 2);
        const int col = bn + (wc << 6) + (ni << 4) + i16;
        const int bb = row0 >> 11, ss = row0 & (NS - 1);
        const int hh = col >> 6, dd = col & 63;
        f16x4 hv;
#pragma unroll
        for (int j = 0; j < 4; ++j) hv[j] = (_Float16)acc[mi][ni][j];
        *(f16x4*)&VhT[(((size_t)(bb * NH + hh) * NHD + dd) << 11) + ss] = hv;
      }
  } else {
    const float scale = which == 0 ? 0.125f : 1.0f;   // fold 1/sqrt(HD) into Q
    _Float16* Out = which == 0 ? Qh : Kh;
#pragma unroll
    for (int mi = 0; mi < 4; ++mi)
#pragma unroll
      for (int ni = 0; ni < 4; ++ni)
#pragma unroll
        for (int j = 0; j < 4; ++j) {
          const int row = bm + (wr << 6) + (mi << 4) + (g4 << 2) + j;
          const int col = bn + (wc << 6) + (ni << 4) + i16;
          const int bb = row >> 11, ss = row & (NS - 1);
          const int hh = col >> 6, dd = col & 63;
          Out[(((size_t)(bb * NH + hh) * NS + ss) << 6) + dd] = (_Float16)(acc[mi][ni][j] * scale);
        }
  }
}

// ---------- flash attention: dbuf prefetch, swizzled gload_lds K/Vt, ctx in place over Qh ----------
__global__ __launch_bounds__(256) void attn_kernel(_Float16* __restrict__ Qc,
                                                   const _Float16* __restrict__ Kh,
                                                   const _Float16* __restrict__ VhT,
                                                   const int* __restrict__ valid_lens) {
  __shared__ alignas(16) _Float16 Ks[2][4096];
  __shared__ alignas(16) _Float16 Vt[2][4096];
  __shared__ alignas(16) _Float16 Ps[64][72];

  // remap: XCD x handles bh {x, x+8, x+16, x+24} (batch-interleaved), q-tiles grouped in time
  const int b0 = blockIdx.x;
  const int idx = ((b0 & 7) << 5) + ((b0 >> 8) << 8) + ((b0 >> 3) & 31);
  const int bh = idx >> 5, qt = idx & 31;
  const int valid = valid_lens[bh >> 4];
  const int tid = threadIdx.x, lane = tid & 63, w = tid >> 6;
  const int i16 = lane & 15, g4 = lane >> 4;

  _Float16* Qb = Qc + ((size_t)bh * NS + (qt << 6)) * NHD;
  const _Float16* Kb = Kh + (size_t)bh * NS * NHD;
  const _Float16* Vb = VhT + (size_t)bh * NHD * NS;   // [d][s]

  f16x8 qf[2];
#pragma unroll
  for (int dc = 0; dc < 2; ++dc)
    qf[dc] = *(const f16x8*)(Qb + (size_t)((w << 4) + i16) * NHD + (dc << 5) + (g4 << 3));

  f32x4 acc[4] = {};
  float mrow[4] = {-1e30f, -1e30f, -1e30f, -1e30f};
  float lsum[4] = {0.f, 0.f, 0.f, 0.f};

  auto STAGE = [&](int buf, int t) {
#pragma unroll
    for (int u = 0; u < 2; ++u) {
      const int cb = ((w << 1) + u) << 6;
      const int c = cb + lane;
      const int r = c >> 3, sl = c & 7;
      const int so = (sl ^ (r & 7)) << 3;   // pre-swizzled source unit
      __builtin_amdgcn_global_load_lds(
          (gas_t)(const void*)(Kb + (size_t)((t << 6) + r) * NHD + so),
          (las_t)(void*)&Ks[buf][cb << 3], 16, 0, 0);
      __builtin_amdgcn_global_load_lds(
          (gas_t)(const void*)(Vb + (size_t)r * NS + (t << 6) + so),
          (las_t)(void*)&Vt[buf][cb << 3], 16, 0, 0);
    }
  };

  const int ntiles = (valid + 63) >> 6;
  STAGE(0, 0);

  for (int t = 0; t < ntiles; ++t) {
    __syncthreads();                      // compiler drains vmcnt before barrier -> tile t ready
    if (t + 1 < ntiles) STAGE((t + 1) & 1, t + 1);
    const int buf = t & 1;
    const bool full = ((t + 1) << 6) <= valid;

    // QK^T (Q pre-scaled by 1/8)
    float pj[4][4];
#pragma unroll
    for (int cf = 0; cf < 4; ++cf) {
      f32x4 sa = {};
      const int r = (cf << 4) + i16;
#pragma unroll
      for (int dc = 0; dc < 2; ++dc) {
        f16x8 kf = *(const f16x8*)&Ks[buf][(r << 6) + ((((dc << 2) + g4) ^ (r & 7)) << 3)];
        sa = __builtin_amdgcn_mfma_f32_16x16x32_f16(qf[dc], kf, sa, 0, 0, 0);
      }
      if (full) {
#pragma unroll
        for (int j = 0; j < 4; ++j) pj[cf][j] = sa[j];
      } else {
        const int kvcol = (t << 6) + r;
#pragma unroll
        for (int j = 0; j < 4; ++j) pj[cf][j] = (kvcol >= valid) ? NEG : sa[j];
      }
    }

    // online softmax (rows = w*16 + 4*g4 + j)
    float tmax[4];
#pragma unroll
    for (int j = 0; j < 4; ++j)
      tmax[j] = fmaxf(fmaxf(pj[0][j], pj[1][j]), fmaxf(pj[2][j], pj[3][j]));
    for (int off = 1; off < 16; off <<= 1)
#pragma unroll
      for (int j = 0; j < 4; ++j)
        tmax[j] = fmaxf(tmax[j], __shfl_xor(tmax[j], off, 64));

    float rowsum[4] = {0.f, 0.f, 0.f, 0.f};
#pragma unroll
    for (int j = 0; j < 4; ++j) {
      const float mn = fmaxf(mrow[j], tmax[j]);
      const float scv = __expf(mrow[j] - mn);
      mrow[j] = mn;
      lsum[j] *= scv;
#pragma unroll
      for (int dn = 0; dn < 4; ++dn) acc[dn][j] *= scv;
    }
#pragma unroll
    for (int cf = 0; cf < 4; ++cf)
#pragma unroll
      for (int j = 0; j < 4; ++j) {
        const float p = __expf(pj[cf][j] - mrow[j]);
        rowsum[j] += p;
        Ps[(w << 4) + (g4 << 2) + j][(cf << 4) + i16] = (_Float16)p;
      }
    for (int off = 1; off < 16; off <<= 1)
#pragma unroll
      for (int j = 0; j < 4; ++j)
        rowsum[j] += __shfl_xor(rowsum[j], off, 64);
#pragma unroll
    for (int j = 0; j < 4; ++j) lsum[j] += rowsum[j];

    // PV: ctx += P @ V (own-wave P rows; compiler orders ds_write->ds_read)
#pragma unroll
    for (int ks = 0; ks < 2; ++ks) {
      f16x8 pf = *(const f16x8*)&Ps[(w << 4) + i16][(ks << 5) + (g4 << 3)];
#pragma unroll
      for (int dn = 0; dn < 4; ++dn) {
        const int d = (dn << 4) + i16;
        f16x8 vf = *(const f16x8*)&Vt[buf][(d << 6) + ((((ks << 2) + g4) ^ (d & 7)) << 3)];
        acc[dn] = __builtin_amdgcn_mfma_f32_16x16x32_f16(pf, vf, acc[dn], 0, 0, 0);
      }
    }
  }

  // epilogue: ctx overwrites this block's own Q rows (split-head layout)
#pragma unroll
  for (int dn = 0; dn < 4; ++dn)
#pragma unroll
    for (int j = 0; j < 4; ++j) {
      const int qrow = (w << 4) + (g4 << 2) + j;
      Qb[(size_t)qrow * NHD + (dn << 4) + i16] = (_Float16)(acc[dn][j] / lsum[j]);
    }
}

// ---------- output GEMM: ctx(split-head fp16) @ Wo^T -> fp32 ----------
__global__ __launch_bounds__(256) void out_kernel(const _Float16* __restrict__ ctx,
                                                  const _Float16* __restrict__ Wot,
                                                  float* __restrict__ Out) {
  constexpr int BK = 32;
  __shared__ alignas(16) _Float16 As[128 * BK];
  __shared__ alignas(16) _Float16 Bs[64 * BK];

  const int idx = ((blockIdx.x % 64) << 3) + (blockIdx.x / 64);
  const int bm = (idx >> 4) << 7;
  const int bn = (idx & 15) << 6;

  const int tid = threadIdx.x, lane = tid & 63, w = tid >> 6;
  const int i16 = lane & 15, g4 = lane >> 4;
  const int wr = w >> 1, wc = w & 1;

  f32x4 acc[4][2] = {};

  for (int kt = 0; kt < GK / BK; ++kt) {
    // A from split-head ctx
#pragma unroll
    for (int u = 0; u < 2; ++u) {
      const int cb = ((w << 1) + u) << 6;
      const int c = cb + lane;
      const int r = c >> 2, sl = c & 3;
      const int m = bm + r;
      const int kcol = (kt << 5) + ((sl ^ (r & 3)) << 3);
      const int bb = m >> 11, ss = m & (NS - 1);
      const int hh = kcol >> 6, dd = kcol & 63;
      __builtin_amdgcn_global_load_lds(
          (gas_t)(const void*)(ctx + (((size_t)(bb * NH + hh) * NS + ss) << 6) + dd),
          (las_t)(void*)&As[cb << 3], 16, 0, 0);
    }
    // B
    {
      const int cb = w << 6;
      const int c = cb + lane;
      const int r = c >> 2, sl = c & 3;
      __builtin_amdgcn_global_load_lds(
          (gas_t)(const void*)(Wot + (size_t)(bn + r) * GK + (kt << 5) + ((sl ^ (r & 3)) << 3)),
          (las_t)(void*)&Bs[cb << 3], 16, 0, 0);
    }
    __syncthreads();

    f16x8 af[4], bf[2];
#pragma unroll
    for (int mi = 0; mi < 4; ++mi) {
      const int r = (wr << 6) + (mi << 4) + i16;
      af[mi] = *(const f16x8*)&As[(r << 5) + ((g4 ^ (r & 3)) << 3)];
    }
#pragma unroll
    for (int ni = 0; ni < 2; ++ni) {
      const int r = (wc << 5) + (ni << 4) + i16;
      bf[ni] = *(const f16x8*)&Bs[(r << 5) + ((g4 ^ (r & 3)) << 3)];
    }
#pragma unroll
    for (int mi = 0; mi < 4; ++mi)
#pragma unroll
      for (int ni = 0; ni < 2; ++ni)
        acc[mi][ni] = __builtin_amdgcn_mfma_f32_16x16x32_f16(af[mi], bf[ni], acc[mi][ni], 0, 0, 0);
    __syncthreads();
  }

#pragma unroll
  for (int mi = 0; mi < 4; ++mi)
#pragma unroll
    for (int ni = 0; ni < 2; ++ni)
#pragma unroll
      for (int j = 0; j < 4; ++j) {
        const int row = bm + (wr << 6) + (mi << 4) + (g4 << 2) + j;
        const int col = bn + (wc << 5) + (ni << 4) + i16;
        Out[(size_t)row * ND + col] = acc[mi][ni][j];
      }
}

extern "C" void kernel_launch(void* const* d_in, const int* in_sizes, int n_in,
                              void* d_out, int out_size, void* d_ws, size_t ws_size,
                              hipStream_t stream) {
  const float* q  = (const float*)d_in[0];
  const float* k  = (const float*)d_in[1];
  const float* v  = (const float*)d_in[2];
  const int*   vl = (const int*)d_in[3];
  const float* Wq = (const float*)d_in[4];
  const float* Wk = (const float*)d_in[5];
  const float* Wv = (const float*)d_in[6];
  const float* Wo = (const float*)d_in[7];

  _Float16* ws = (_Float16*)d_ws;
  _Float16* Qh  = ws;                        // 8 MB, becomes ctx in place
  _Float16* Kh  = ws + 4194304;              // 8 MB
  _Float16* VhT = ws + 8388608;              // 8 MB, [b,h,d,s]
  _Float16* Wt  = ws + 12582912;             // 4 x 2 MB transposed weights

  wt_kernel<<<dim3(1024), dim3(256), 0, stream>>>(Wq, Wk, Wv, Wo, Wt);
  proj_kernel<<<dim3(768), dim3(256), 0, stream>>>(q, k, v, Wt, Qh, Kh, VhT);
  attn_kernel<<<dim3(NB * NH * (NS >> 6)), dim3(256), 0, stream>>>(Qh, Kh, VhT, vl);
  out_kernel<<<dim3(512), dim3(256), 0, stream>>>(Qh, Wt + 3145728, (float*)d_out);
}

// Round 5
// 214.335 us; speedup vs baseline: 1.6939x; 1.0551x over previous
//
#include <hip/hip_runtime.h>
#include <math.h>

#define NB 2
#define NS 2048
#define ND 1024
#define NH 16
#define NHD 64
#define GK 1024
#define NEG -1000000.0f

typedef __attribute__((ext_vector_type(4))) float f32x4;
typedef __attribute__((ext_vector_type(8))) _Float16 f16x8;
typedef __attribute__((ext_vector_type(4))) _Float16 f16x4;
typedef __attribute__((ext_vector_type(2))) __fp16 fp16x2_t;

typedef const __attribute__((address_space(1))) unsigned int* gas_t;
typedef __attribute__((address_space(3))) unsigned int* las_t;

// ---------- prep: W fp32 [K][N] -> Wt fp16 [N][K] (x4)  +  x fp32 -> fp16 (x3) ----------
__global__ __launch_bounds__(256) void prep_kernel(const float* __restrict__ Wq,
                                                   const float* __restrict__ Wk,
                                                   const float* __restrict__ Wv,
                                                   const float* __restrict__ Wo,
                                                   const float* __restrict__ xq,
                                                   const float* __restrict__ xk,
                                                   const float* __restrict__ xv,
                                                   _Float16* __restrict__ WtBase,
                                                   _Float16* __restrict__ xhq,
                                                   _Float16* __restrict__ xhk,
                                                   _Float16* __restrict__ xhv) {
  const int t = threadIdx.x;
  if (blockIdx.x < 1024) {
    __shared__ _Float16 Ts[64][72];
    const int which = blockIdx.x >> 8;
    const int rem = blockIdx.x & 255;
    const int tk = rem >> 4;
    const int tn = rem & 15;
    const float* W = which == 0 ? Wq : which == 1 ? Wk : which == 2 ? Wv : Wo;
    _Float16* Wt = WtBase + (size_t)which * (GK * ND);
#pragma unroll
    for (int p = 0; p < 4; ++p) {
      const int kr = (p << 4) + (t >> 4);
      const int nc = (t & 15) << 2;
      float4 v = *(const float4*)(W + (size_t)((tk << 6) + kr) * ND + (tn << 6) + nc);
      f16x4 h = {(_Float16)v.x, (_Float16)v.y, (_Float16)v.z, (_Float16)v.w};
      *(f16x4*)&Ts[kr][nc] = h;
    }
    __syncthreads();
#pragma unroll
    for (int p = 0; p < 4; ++p) {
      const int nr = (p << 4) + (t >> 4);
      const int kc = (t & 15) << 2;
      f16x4 h;
#pragma unroll
      for (int u = 0; u < 4; ++u) h[u] = Ts[kc + u][nr];
      *(f16x4*)(Wt + (size_t)((tn << 6) + nr) * GK + (tk << 6) + kc) = h;
    }
  } else {
    const int cid = blockIdx.x - 1024;            // 0..6143
    const int which = cid >> 11;                  // 2048 blocks per input
    const float* src = which == 0 ? xq : which == 1 ? xk : xv;
    _Float16* dst = which == 0 ? xhq : which == 1 ? xhk : xhv;
    const size_t e0 = ((((size_t)(cid & 2047)) << 8) + t) << 3;
    float4 v0 = *(const float4*)(src + e0);
    float4 v1 = *(const float4*)(src + e0 + 4);
    f16x8 h;
#pragma unroll
    for (int j = 0; j < 4; ++j) { h[j] = (_Float16)(&v0.x)[j]; h[4 + j] = (_Float16)(&v1.x)[j]; }
    *(f16x8*)(dst + e0) = h;
  }
}

// ---------- pure-fp16 128-tile GEMM, gload_lds both operands ----------
// MODE 0: QK fused (BN=128, which=grid half): out split-head, Q scaled 0.125
// MODE 1: V (BN=64): out transposed VhT[b,h,d,s]
template<int MODE>
__global__ __launch_bounds__(256) void gemm16_kernel(const _Float16* __restrict__ A0,
                                                     const _Float16* __restrict__ A1,
                                                     const _Float16* __restrict__ Bt0,
                                                     _Float16* __restrict__ O0,
                                                     _Float16* __restrict__ O1) {
  constexpr int BN = (MODE == 0) ? 128 : 64;
  constexpr int NF = BN / 32;
  __shared__ alignas(16) _Float16 As[128 * 32];
  __shared__ alignas(16) _Float16 Bs[BN * 32];

  const int b = blockIdx.x;
  const int wg = ((b & 7) << 6) + (b >> 3);       // XCD-grouped, bijective for 512
  int which, bm, bn;
  if (MODE == 0) {
    which = wg >> 8;
    const int rem = wg & 255;
    bm = (rem >> 3) << 7;
    bn = (rem & 7) << 7;
  } else {
    which = 0;
    bm = (wg >> 4) << 7;
    bn = (wg & 15) << 6;
  }
  const _Float16* A = (MODE == 0 && which == 1) ? A1 : A0;
  const _Float16* Bt = Bt0 + (size_t)which * (ND * GK);

  const int tid = threadIdx.x, lane = tid & 63, w = tid >> 6;
  const int i16 = lane & 15, g4 = lane >> 4;
  const int wr = w >> 1, wc = w & 1;

  f32x4 acc[4][NF] = {};

  for (int kt = 0; kt < GK / 32; ++kt) {
    // A: 128x32 fp16
#pragma unroll
    for (int u = 0; u < 2; ++u) {
      const int cb = ((w << 1) + u) << 6;
      const int c = cb + lane;
      const int r = c >> 2, sl = c & 3;
      __builtin_amdgcn_global_load_lds(
          (gas_t)(const void*)(A + (size_t)(bm + r) * GK + (kt << 5) + ((sl ^ (r & 3)) << 3)),
          (las_t)(void*)&As[cb << 3], 16, 0, 0);
    }
    // B: BNx32 fp16
#pragma unroll
    for (int u = 0; u < BN / 64; ++u) {
      const int cb = ((w * (BN / 64)) + u) << 6;
      const int c = cb + lane;
      const int r = c >> 2, sl = c & 3;
      __builtin_amdgcn_global_load_lds(
          (gas_t)(const void*)(Bt + (size_t)(bn + r) * GK + (kt << 5) + ((sl ^ (r & 3)) << 3)),
          (las_t)(void*)&Bs[cb << 3], 16, 0, 0);
    }
    __syncthreads();

    f16x8 af[4], bf[NF];
#pragma unroll
    for (int mi = 0; mi < 4; ++mi) {
      const int r = (wr << 6) + (mi << 4) + i16;
      af[mi] = *(const f16x8*)&As[(r << 5) + ((g4 ^ (r & 3)) << 3)];
    }
#pragma unroll
    for (int ni = 0; ni < NF; ++ni) {
      const int r = wc * (BN / 2) + (ni << 4) + i16;
      bf[ni] = *(const f16x8*)&Bs[(r << 5) + ((g4 ^ (r & 3)) << 3)];
    }
#pragma unroll
    for (int mi = 0; mi < 4; ++mi)
#pragma unroll
      for (int ni = 0; ni < NF; ++ni)
        acc[mi][ni] = __builtin_amdgcn_mfma_f32_16x16x32_f16(af[mi], bf[ni], acc[mi][ni], 0, 0, 0);
    __syncthreads();
  }

  if (MODE == 1) {
    // transposed V output
#pragma unroll
    for (int mi = 0; mi < 4; ++mi)
#pragma unroll
      for (int ni = 0; ni < NF; ++ni) {
        const int row0 = bm + (wr << 6) + (mi << 4) + (g4 << 2);
        const int col = bn + wc * (BN / 2) + (ni << 4) + i16;
        const int bb = row0 >> 11, ss = row0 & (NS - 1);
        const int hh = col >> 6, dd = col & 63;
        f16x4 hv;
#pragma unroll
        for (int j = 0; j < 4; ++j) hv[j] = (_Float16)acc[mi][ni][j];
        *(f16x4*)&O0[(((size_t)(bb * NH + hh) * NHD + dd) << 11) + ss] = hv;
      }
  } else {
    const float scale = (which == 0) ? 0.125f : 1.0f;
    _Float16* Out = (which == 0) ? O0 : O1;
#pragma unroll
    for (int mi = 0; mi < 4; ++mi)
#pragma unroll
      for (int ni = 0; ni < NF; ++ni)
#pragma unroll
        for (int j = 0; j < 4; ++j) {
          const int row = bm + (wr << 6) + (mi << 4) + (g4 << 2) + j;
          const int col = bn + wc * (BN / 2) + (ni << 4) + i16;
          const int bb = row >> 11, ss = row & (NS - 1);
          const int hh = col >> 6, dd = col & 63;
          Out[(((size_t)(bb * NH + hh) * NS + ss) << 6) + dd] = (_Float16)(acc[mi][ni][j] * scale);
        }
  }
}

// ---------- flash attention: swapped QK^T, in-register softmax, defer-max ----------
__global__ __launch_bounds__(256) void attn_kernel(_Float16* __restrict__ Qc,
                                                   const _Float16* __restrict__ Kh,
                                                   const _Float16* __restrict__ VhT,
                                                   const int* __restrict__ valid_lens) {
  __shared__ alignas(16) _Float16 Ks[2][4096];
  __shared__ alignas(16) _Float16 Vt[2][4096];
  __shared__ alignas(16) unsigned int PsW[2048];   // [64 rows][32 u32], XOR-swizzled 16B chunks

  const int b0 = blockIdx.x;
  const int idx = ((b0 & 7) << 5) + ((b0 >> 8) << 8) + ((b0 >> 3) & 31);
  const int bh = idx >> 5, qt = idx & 31;
  const int valid = valid_lens[bh >> 4];
  const int tid = threadIdx.x, lane = tid & 63, w = tid >> 6;
  const int i16 = lane & 15, g4 = lane >> 4;
  const int qrow = (w << 4) + i16;                 // this lane's q row (softmax side)

  _Float16* Qb = Qc + ((size_t)bh * NS + (qt << 6)) * NHD;
  const _Float16* Kb = Kh + (size_t)bh * NS * NHD;
  const _Float16* Vb = VhT + (size_t)bh * NHD * NS;

  f16x8 qf[2];
#pragma unroll
  for (int dc = 0; dc < 2; ++dc)
    qf[dc] = *(const f16x8*)(Qb + (size_t)qrow * NHD + (dc << 5) + (g4 << 3));

  f32x4 acc[4] = {};
  float mrow = -1e30f;
  float lsum = 0.f;

  auto STAGE = [&](int buf, int t) {
#pragma unroll
    for (int u = 0; u < 2; ++u) {
      const int cb = ((w << 1) + u) << 6;
      const int c = cb + lane;
      const int r = c >> 3, sl = c & 7;
      const int so = (sl ^ (r & 7)) << 3;
      __builtin_amdgcn_global_load_lds(
          (gas_t)(const void*)(Kb + (size_t)((t << 6) + r) * NHD + so),
          (las_t)(void*)&Ks[buf][cb << 3], 16, 0, 0);
      __builtin_amdgcn_global_load_lds(
          (gas_t)(const void*)(Vb + (size_t)r * NS + (t << 6) + so),
          (las_t)(void*)&Vt[buf][cb << 3], 16, 0, 0);
    }
  };

  const int ntiles = (valid + 63) >> 6;
  STAGE(0, 0);

  for (int t = 0; t < ntiles; ++t) {
    __syncthreads();                      // drains vmcnt -> tile t staged
    if (t + 1 < ntiles) STAGE((t + 1) & 1, t + 1);
    const int buf = t & 1;
    const bool full = ((t + 1) << 6) <= valid;

    // QK^T swapped: C = P^T frag -> lane holds P[q=qrow][kv = t*64 + 16cf + 4g4 + j]
    float pj[4][4];
#pragma unroll
    for (int cf = 0; cf < 4; ++cf) {
      f32x4 sa = {};
      const int r = (cf << 4) + i16;
#pragma unroll
      for (int dc = 0; dc < 2; ++dc) {
        f16x8 kf = *(const f16x8*)&Ks[buf][(r << 6) + ((((dc << 2) + g4) ^ (r & 7)) << 3)];
        sa = __builtin_amdgcn_mfma_f32_16x16x32_f16(kf, qf[dc], sa, 0, 0, 0);
      }
      if (full) {
#pragma unroll
        for (int j = 0; j < 4; ++j) pj[cf][j] = sa[j];
      } else {
        const int kvb = (t << 6) + (cf << 4) + (g4 << 2);
#pragma unroll
        for (int j = 0; j < 4; ++j) pj[cf][j] = (kvb + j >= valid) ? NEG : sa[j];
      }
    }

    // in-lane row max + cross-g4 reduce (2 shfl)
    float m16 = pj[0][0];
#pragma unroll
    for (int cf = 0; cf < 4; ++cf)
#pragma unroll
      for (int j = 0; j < 4; ++j) m16 = fmaxf(m16, pj[cf][j]);
    m16 = fmaxf(m16, __shfl_xor(m16, 16, 64));
    m16 = fmaxf(m16, __shfl_xor(m16, 32, 64));

    // defer-max rescale (rare)
    if (__any(m16 > mrow + 8.0f)) {
      const float mn = fmaxf(mrow, m16);
      const float scv = __expf(mrow - mn);
      mrow = mn;
      lsum *= scv;
#pragma unroll
      for (int j = 0; j < 4; ++j) {
        const float sj = __shfl(scv, (g4 << 2) + j, 64);   // scv of acc row q=4g4+j
#pragma unroll
        for (int dn = 0; dn < 4; ++dn) acc[dn][j] *= sj;
      }
    }

    // p = exp(pj - mrow); pack and store 4x ds_write_b64 into swizzled Ps
    float rsum = 0.f;
#pragma unroll
    for (int cf = 0; cf < 4; ++cf) {
      float p0 = __expf(pj[cf][0] - mrow);
      float p1 = __expf(pj[cf][1] - mrow);
      float p2 = __expf(pj[cf][2] - mrow);
      float p3 = __expf(pj[cf][3] - mrow);
      rsum += (p0 + p1) + (p2 + p3);
      union { fp16x2_t h; unsigned int u; } ca, cb2;
      ca.h = __builtin_amdgcn_cvt_pkrtz(p0, p1);
      cb2.h = __builtin_amdgcn_cvt_pkrtz(p2, p3);
      const int u8 = (cf << 2) + g4;                        // 8B-unit index (cols 4u..4u+3)
      const int s16 = (u8 >> 1) ^ (qrow & 7);               // swizzled 16B chunk
      uint2 dv; dv.x = ca.u; dv.y = cb2.u;
      *(uint2*)&PsW[(qrow << 5) + (s16 << 2) + ((u8 & 1) << 1)] = dv;
    }
    rsum += __shfl_xor(rsum, 16, 64);
    rsum += __shfl_xor(rsum, 32, 64);
    lsum += rsum;

    // PV: pf = A-frag of P (row q=qrow, kv contiguous) from swizzled Ps
#pragma unroll
    for (int ks = 0; ks < 2; ++ks) {
      const int cr = (ks << 2) + g4;
      f16x8 pf = *(const f16x8*)&PsW[(qrow << 5) + ((cr ^ (qrow & 7)) << 2)];
#pragma unroll
      for (int dn = 0; dn < 4; ++dn) {
        const int d = (dn << 4) + i16;
        f16x8 vf = *(const f16x8*)&Vt[buf][(d << 6) + ((((ks << 2) + g4) ^ (d & 7)) << 3)];
        acc[dn] = __builtin_amdgcn_mfma_f32_16x16x32_f16(pf, vf, acc[dn], 0, 0, 0);
      }
    }
  }

  // epilogue: acc rows are q = w*16 + 4g4 + j; fetch their lsum via shfl
  float linv[4];
#pragma unroll
  for (int j = 0; j < 4; ++j)
    linv[j] = 1.0f / __shfl(lsum, (g4 << 2) + j, 64);
#pragma unroll
  for (int dn = 0; dn < 4; ++dn)
#pragma unroll
    for (int j = 0; j < 4; ++j) {
      const int qr = (w << 4) + (g4 << 2) + j;
      Qb[(size_t)qr * NHD + (dn << 4) + i16] = (_Float16)(acc[dn][j] * linv[j]);
    }
}

// ---------- output GEMM: ctx(split-head fp16) @ Wo^T -> fp32 ----------
__global__ __launch_bounds__(256) void out_kernel(const _Float16* __restrict__ ctx,
                                                  const _Float16* __restrict__ Wot,
                                                  float* __restrict__ Out) {
  constexpr int BK = 32;
  __shared__ alignas(16) _Float16 As[128 * BK];
  __shared__ alignas(16) _Float16 Bs[64 * BK];

  const int idx = ((blockIdx.x % 64) << 3) + (blockIdx.x / 64);
  const int bm = (idx >> 4) << 7;
  const int bn = (idx & 15) << 6;

  const int tid = threadIdx.x, lane = tid & 63, w = tid >> 6;
  const int i16 = lane & 15, g4 = lane >> 4;
  const int wr = w >> 1, wc = w & 1;

  f32x4 acc[4][2] = {};

  for (int kt = 0; kt < GK / BK; ++kt) {
#pragma unroll
    for (int u = 0; u < 2; ++u) {
      const int cb = ((w << 1) + u) << 6;
      const int c = cb + lane;
      const int r = c >> 2, sl = c & 3;
      const int m = bm + r;
      const int kcol = (kt << 5) + ((sl ^ (r & 3)) << 3);
      const int bb = m >> 11, ss = m & (NS - 1);
      const int hh = kcol >> 6, dd = kcol & 63;
      __builtin_amdgcn_global_load_lds(
          (gas_t)(const void*)(ctx + (((size_t)(bb * NH + hh) * NS + ss) << 6) + dd),
          (las_t)(void*)&As[cb << 3], 16, 0, 0);
    }
    {
      const int cb = w << 6;
      const int c = cb + lane;
      const int r = c >> 2, sl = c & 3;
      __builtin_amdgcn_global_load_lds(
          (gas_t)(const void*)(Wot + (size_t)(bn + r) * GK + (kt << 5) + ((sl ^ (r & 3)) << 3)),
          (las_t)(void*)&Bs[cb << 3], 16, 0, 0);
    }
    __syncthreads();

    f16x8 af[4], bf[2];
#pragma unroll
    for (int mi = 0; mi < 4; ++mi) {
      const int r = (wr << 6) + (mi << 4) + i16;
      af[mi] = *(const f16x8*)&As[(r << 5) + ((g4 ^ (r & 3)) << 3)];
    }
#pragma unroll
    for (int ni = 0; ni < 2; ++ni) {
      const int r = (wc << 5) + (ni << 4) + i16;
      bf[ni] = *(const f16x8*)&Bs[(r << 5) + ((g4 ^ (r & 3)) << 3)];
    }
#pragma unroll
    for (int mi = 0; mi < 4; ++mi)
#pragma unroll
      for (int ni = 0; ni < 2; ++ni)
        acc[mi][ni] = __builtin_amdgcn_mfma_f32_16x16x32_f16(af[mi], bf[ni], acc[mi][ni], 0, 0, 0);
    __syncthreads();
  }

#pragma unroll
  for (int mi = 0; mi < 4; ++mi)
#pragma unroll
    for (int ni = 0; ni < 2; ++ni)
#pragma unroll
      for (int j = 0; j < 4; ++j) {
        const int row = bm + (wr << 6) + (mi << 4) + (g4 << 2) + j;
        const int col = bn + (wc << 5) + (ni << 4) + i16;
        Out[(size_t)row * ND + col] = acc[mi][ni][j];
      }
}

extern "C" void kernel_launch(void* const* d_in, const int* in_sizes, int n_in,
                              void* d_out, int out_size, void* d_ws, size_t ws_size,
                              hipStream_t stream) {
  const float* q  = (const float*)d_in[0];
  const float* k  = (const float*)d_in[1];
  const float* v  = (const float*)d_in[2];
  const int*   vl = (const int*)d_in[3];
  const float* Wq = (const float*)d_in[4];
  const float* Wk = (const float*)d_in[5];
  const float* Wv = (const float*)d_in[6];
  const float* Wo = (const float*)d_in[7];

  _Float16* ws = (_Float16*)d_ws;
  _Float16* Qh  = ws;                        // phase1: xh_v ; phase2+: Qh/ctx
  _Float16* Kh  = ws + 4194304;
  _Float16* VhT = ws + 8388608;
  _Float16* Wt  = ws + 12582912;             // 4 x 1M f16 (q,k,v,o)

  _Float16* xhq = (_Float16*)d_out;          // d_out as 8M-f16 scratch until out_kernel
  _Float16* xhk = xhq + 4194304;
  _Float16* xhv = Qh;

  prep_kernel<<<dim3(7168), dim3(256), 0, stream>>>(Wq, Wk, Wv, Wo, q, k, v, Wt, xhq, xhk, xhv);
  gemm16_kernel<1><<<dim3(512), dim3(256), 0, stream>>>(xhv, xhv, Wt + 2097152, VhT, VhT);
  gemm16_kernel<0><<<dim3(512), dim3(256), 0, stream>>>(xhq, xhk, Wt, Qh, Kh);
  attn_kernel<<<dim3(NB * NH * (NS >> 6)), dim3(256), 0, stream>>>(Qh, Kh, VhT, vl);
  out_kernel<<<dim3(512), dim3(256), 0, stream>>>(Qh, Wt + 3145728, (float*)d_out);
}

// Round 7
// 203.222 us; speedup vs baseline: 1.7865x; 1.0547x over previous
//
#include <hip/hip_runtime.h>
#include <math.h>

#define NB 2
#define NS 2048
#define ND 1024
#define NH 16
#define NHD 64
#define GK 1024
#define NEG -1000000.0f

typedef __attribute__((ext_vector_type(4))) float f32x4;
typedef __attribute__((ext_vector_type(8))) _Float16 f16x8;
typedef __attribute__((ext_vector_type(4))) _Float16 f16x4;
typedef __attribute__((ext_vector_type(2))) __fp16 fp16x2_t;

typedef const __attribute__((address_space(1))) unsigned int* gas_t;
typedef __attribute__((address_space(3))) unsigned int* las_t;

// ---------- prep: W fp32 [K][N] -> Wt fp16 [N][K] (x4) ----------
__global__ __launch_bounds__(256) void prep_kernel(const float* __restrict__ Wq,
                                                   const float* __restrict__ Wk,
                                                   const float* __restrict__ Wv,
                                                   const float* __restrict__ Wo,
                                                   _Float16* __restrict__ WtBase) {
  __shared__ _Float16 Ts[64][72];
  const int which = blockIdx.x >> 8;
  const int rem = blockIdx.x & 255;
  const int tk = rem >> 4;
  const int tn = rem & 15;
  const float* W = which == 0 ? Wq : which == 1 ? Wk : which == 2 ? Wv : Wo;
  _Float16* Wt = WtBase + (size_t)which * (GK * ND);
  const int t = threadIdx.x;
#pragma unroll
  for (int p = 0; p < 4; ++p) {
    const int kr = (p << 4) + (t >> 4);
    const int nc = (t & 15) << 2;
    float4 v = *(const float4*)(W + (size_t)((tk << 6) + kr) * ND + (tn << 6) + nc);
    f16x4 h = {(_Float16)v.x, (_Float16)v.y, (_Float16)v.z, (_Float16)v.w};
    *(f16x4*)&Ts[kr][nc] = h;
  }
  __syncthreads();
#pragma unroll
  for (int p = 0; p < 4; ++p) {
    const int nr = (p << 4) + (t >> 4);
    const int kc = (t & 15) << 2;
    f16x4 h;
#pragma unroll
    for (int u = 0; u < 4; ++u) h[u] = Ts[kc + u][nr];
    *(f16x4*)(Wt + (size_t)((tn << 6) + nr) * GK + (tk << 6) + kc) = h;
  }
}

// ---------- fused Q/K/V projection: A fp32 reg-staged+cvt, B fp16 gload_lds ----------
// which 0: Qh (scaled 0.125*log2e), 1: Kh, 2: VhT transposed [b,h,d,s]
__global__ __launch_bounds__(256) void proj_kernel(const float* __restrict__ xq,
                                                   const float* __restrict__ xk,
                                                   const float* __restrict__ xv,
                                                   const _Float16* __restrict__ WtBase,
                                                   _Float16* __restrict__ Qh,
                                                   _Float16* __restrict__ Kh,
                                                   _Float16* __restrict__ VhT) {
  __shared__ alignas(16) _Float16 As[128 * 32];
  __shared__ alignas(16) _Float16 Bs[128 * 32];

  const int b = blockIdx.x;
  const int wg = ((b & 7) * 96) + (b >> 3);       // bijective for 768, XCD-grouped
  const int which = wg >> 8;
  const int rem = wg & 255;
  const int bm = (rem >> 3) << 7;
  const int bn = (rem & 7) << 7;
  const float* A = which == 0 ? xq : which == 1 ? xk : xv;
  const _Float16* Bt = WtBase + (size_t)which * (ND * GK);

  const int tid = threadIdx.x, lane = tid & 63, w = tid >> 6;
  const int i16 = lane & 15, g4 = lane >> 4;
  const int wr = w >> 1, wc = w & 1;

  f32x4 acc[4][4] = {};

  for (int kt = 0; kt < GK / 32; ++kt) {
    // ---- A: fp32 load -> cvt -> ds_write_b128 (slot sl holds source col sl^(r&3)) ----
#pragma unroll
    for (int u = 0; u < 2; ++u) {
      const int c = (((w << 1) + u) << 6) + lane;   // 0..511
      const int r = c >> 2, sl = c & 3;
      const float* src = A + (size_t)(bm + r) * GK + (kt << 5) + ((sl ^ (r & 3)) << 3);
      float4 v0 = *(const float4*)src;
      float4 v1 = *(const float4*)(src + 4);
      f16x8 h;
#pragma unroll
      for (int j = 0; j < 4; ++j) { h[j] = (_Float16)(&v0.x)[j]; h[4 + j] = (_Float16)(&v1.x)[j]; }
      *(f16x8*)&As[(r << 5) + (sl << 3)] = h;
    }
    // ---- B via global_load_lds (pre-swizzled source) ----
#pragma unroll
    for (int u = 0; u < 2; ++u) {
      const int cb = ((w << 1) + u) << 6;
      const int c = cb + lane;
      const int r = c >> 2, sl = c & 3;
      __builtin_amdgcn_global_load_lds(
          (gas_t)(const void*)(Bt + (size_t)(bn + r) * GK + (kt << 5) + ((sl ^ (r & 3)) << 3)),
          (las_t)(void*)&Bs[cb << 3], 16, 0, 0);
    }
    __syncthreads();

    f16x8 af[4], bf[4];
#pragma unroll
    for (int mi = 0; mi < 4; ++mi) {
      const int r = (wr << 6) + (mi << 4) + i16;
      af[mi] = *(const f16x8*)&As[(r << 5) + ((g4 ^ (r & 3)) << 3)];
    }
#pragma unroll
    for (int ni = 0; ni < 4; ++ni) {
      const int r = (wc << 6) + (ni << 4) + i16;
      bf[ni] = *(const f16x8*)&Bs[(r << 5) + ((g4 ^ (r & 3)) << 3)];
    }
#pragma unroll
    for (int mi = 0; mi < 4; ++mi)
#pragma unroll
      for (int ni = 0; ni < 4; ++ni)
        acc[mi][ni] = __builtin_amdgcn_mfma_f32_16x16x32_f16(af[mi], bf[ni], acc[mi][ni], 0, 0, 0);
    __syncthreads();
  }

  if (which == 2) {
    // V: transposed VhT[b,h,d,s]; acc j-elems = 4 consecutive s -> f16x4
#pragma unroll
    for (int mi = 0; mi < 4; ++mi)
#pragma unroll
      for (int ni = 0; ni < 4; ++ni) {
        const int row0 = bm + (wr << 6) + (mi << 4) + (g4 << 2);
        const int col = bn + (wc << 6) + (ni << 4) + i16;
        const int bb = row0 >> 11, ss = row0 & (NS - 1);
        const int hh = col >> 6, dd = col & 63;
        f16x4 hv;
#pragma unroll
        for (int j = 0; j < 4; ++j) hv[j] = (_Float16)acc[mi][ni][j];
        *(f16x4*)&VhT[(((size_t)(bb * NH + hh) * NHD + dd) << 11) + ss] = hv;
      }
  } else {
    const float scale = (which == 0) ? 0.125f * 1.44269504f : 1.0f;  // Q in log2-domain
    _Float16* Out = (which == 0) ? Qh : Kh;
#pragma unroll
    for (int mi = 0; mi < 4; ++mi)
#pragma unroll
      for (int ni = 0; ni < 4; ++ni)
#pragma unroll
        for (int j = 0; j < 4; ++j) {
          const int row = bm + (wr << 6) + (mi << 4) + (g4 << 2) + j;
          const int col = bn + (wc << 6) + (ni << 4) + i16;
          const int bb = row >> 11, ss = row & (NS - 1);
          const int hh = col >> 6, dd = col & 63;
          Out[(((size_t)(bb * NH + hh) * NS + ss) << 6) + dd] = (_Float16)(acc[mi][ni][j] * scale);
        }
  }
}

// ---------- flash attention: swapped QK^T, in-register softmax (log2 domain), defer-max ----------
__global__ __launch_bounds__(256) void attn_kernel(_Float16* __restrict__ Qc,
                                                   const _Float16* __restrict__ Kh,
                                                   const _Float16* __restrict__ VhT,
                                                   const int* __restrict__ valid_lens) {
  __shared__ alignas(16) _Float16 Ks[2][4096];
  __shared__ alignas(16) _Float16 Vt[2][4096];
  __shared__ alignas(16) unsigned int PsW[2048];   // [64 rows][32 u32], XOR-swizzled 16B chunks

  const int b0 = blockIdx.x;
  const int idx = ((b0 & 7) << 5) + ((b0 >> 8) << 8) + ((b0 >> 3) & 31);
  const int bh = idx >> 5, qt = idx & 31;
  const int valid = valid_lens[bh >> 4];
  const int tid = threadIdx.x, lane = tid & 63, w = tid >> 6;
  const int i16 = lane & 15, g4 = lane >> 4;
  const int qrow = (w << 4) + i16;                 // this lane's q row (softmax side)

  _Float16* Qb = Qc + ((size_t)bh * NS + (qt << 6)) * NHD;
  const _Float16* Kb = Kh + (size_t)bh * NS * NHD;
  const _Float16* Vb = VhT + (size_t)bh * NHD * NS;

  f16x8 qf[2];
#pragma unroll
  for (int dc = 0; dc < 2; ++dc)
    qf[dc] = *(const f16x8*)(Qb + (size_t)qrow * NHD + (dc << 5) + (g4 << 3));

  f32x4 acc[4] = {};
  float mrow = -1e30f;
  float lsum = 0.f;

  auto STAGE = [&](int buf, int t) {
#pragma unroll
    for (int u = 0; u < 2; ++u) {
      const int cb = ((w << 1) + u) << 6;
      const int c = cb + lane;
      const int r = c >> 3, sl = c & 7;
      const int so = (sl ^ (r & 7)) << 3;
      __builtin_amdgcn_global_load_lds(
          (gas_t)(const void*)(Kb + (size_t)((t << 6) + r) * NHD + so),
          (las_t)(void*)&Ks[buf][cb << 3], 16, 0, 0);
      __builtin_amdgcn_global_load_lds(
          (gas_t)(const void*)(Vb + (size_t)r * NS + (t << 6) + so),
          (las_t)(void*)&Vt[buf][cb << 3], 16, 0, 0);
    }
  };

  const int ntiles = (valid + 63) >> 6;
  STAGE(0, 0);

  for (int t = 0; t < ntiles; ++t) {
    __syncthreads();                      // drains vmcnt -> tile t staged
    if (t + 1 < ntiles) STAGE((t + 1) & 1, t + 1);
    const int buf = t & 1;
    const bool full = ((t + 1) << 6) <= valid;

    // QK^T swapped: lane holds P[q=qrow][kv = t*64 + 16cf + 4g4 + j] (log2-domain scores)
    float pj[4][4];
#pragma unroll
    for (int cf = 0; cf < 4; ++cf) {
      f32x4 sa = {};
      const int r = (cf << 4) + i16;
#pragma unroll
      for (int dc = 0; dc < 2; ++dc) {
        f16x8 kf = *(const f16x8*)&Ks[buf][(r << 6) + ((((dc << 2) + g4) ^ (r & 7)) << 3)];
        sa = __builtin_amdgcn_mfma_f32_16x16x32_f16(kf, qf[dc], sa, 0, 0, 0);
      }
      if (full) {
#pragma unroll
        for (int j = 0; j < 4; ++j) pj[cf][j] = sa[j];
      } else {
        const int kvb = (t << 6) + (cf << 4) + (g4 << 2);
#pragma unroll
        for (int j = 0; j < 4; ++j) pj[cf][j] = (kvb + j >= valid) ? NEG : sa[j];
      }
    }

    // in-lane row max + cross-g4 reduce (2 shfl)
    float m16 = pj[0][0];
#pragma unroll
    for (int cf = 0; cf < 4; ++cf)
#pragma unroll
      for (int j = 0; j < 4; ++j) m16 = fmaxf(m16, pj[cf][j]);
    m16 = fmaxf(m16, __shfl_xor(m16, 16, 64));
    m16 = fmaxf(m16, __shfl_xor(m16, 32, 64));

    // defer-max rescale (rare): P bounded by 2^8
    if (__any(m16 > mrow + 8.0f)) {
      const float mn = fmaxf(mrow, m16);
      const float scv = __builtin_amdgcn_exp2f(mrow - mn);
      mrow = mn;
      lsum *= scv;
#pragma unroll
      for (int j = 0; j < 4; ++j) {
        const float sj = __shfl(scv, (g4 << 2) + j, 64);   // scv of acc row q=4g4+j
#pragma unroll
        for (int dn = 0; dn < 4; ++dn) acc[dn][j] *= sj;
      }
    }

    // p = 2^(pj - mrow); pack and store 4x ds_write_b64 into swizzled Ps
    float rsum = 0.f;
#pragma unroll
    for (int cf = 0; cf < 4; ++cf) {
      float p0 = __builtin_amdgcn_exp2f(pj[cf][0] - mrow);
      float p1 = __builtin_amdgcn_exp2f(pj[cf][1] - mrow);
      float p2 = __builtin_amdgcn_exp2f(pj[cf][2] - mrow);
      float p3 = __builtin_amdgcn_exp2f(pj[cf][3] - mrow);
      rsum += (p0 + p1) + (p2 + p3);
      union { fp16x2_t h; unsigned int u; } ca, cb2;
      ca.h = __builtin_amdgcn_cvt_pkrtz(p0, p1);
      cb2.h = __builtin_amdgcn_cvt_pkrtz(p2, p3);
      const int u8 = (cf << 2) + g4;                        // 8B-unit index (cols 4u..4u+3)
      const int s16 = (u8 >> 1) ^ (qrow & 7);               // swizzled 16B chunk
      uint2 dv; dv.x = ca.u; dv.y = cb2.u;
      *(uint2*)&PsW[(qrow << 5) + (s16 << 2) + ((u8 & 1) << 1)] = dv;
    }
    rsum += __shfl_xor(rsum, 16, 64);
    rsum += __shfl_xor(rsum, 32, 64);
    lsum += rsum;

    // PV: pf = A-frag of P (row q=qrow, kv contiguous) from swizzled Ps
#pragma unroll
    for (int ks = 0; ks < 2; ++ks) {
      const int cr = (ks << 2) + g4;
      f16x8 pf = *(const f16x8*)&PsW[(qrow << 5) + ((cr ^ (qrow & 7)) << 2)];
#pragma unroll
      for (int dn = 0; dn < 4; ++dn) {
        const int d = (dn << 4) + i16;
        f16x8 vf = *(const f16x8*)&Vt[buf][(d << 6) + ((((ks << 2) + g4) ^ (d & 7)) << 3)];
        acc[dn] = __builtin_amdgcn_mfma_f32_16x16x32_f16(pf, vf, acc[dn], 0, 0, 0);
      }
    }
  }

  // epilogue: acc rows are q = w*16 + 4g4 + j; fetch their lsum via shfl
  float linv[4];
#pragma unroll
  for (int j = 0; j < 4; ++j)
    linv[j] = 1.0f / __shfl(lsum, (g4 << 2) + j, 64);
#pragma unroll
  for (int dn = 0; dn < 4; ++dn)
#pragma unroll
    for (int j = 0; j < 4; ++j) {
      const int qr = (w << 4) + (g4 << 2) + j;
      Qb[(size_t)qr * NHD + (dn << 4) + i16] = (_Float16)(acc[dn][j] * linv[j]);
    }
}

// ---------- output GEMM: ctx(split-head fp16) @ Wo^T -> fp32 ----------
__global__ __launch_bounds__(256) void out_kernel(const _Float16* __restrict__ ctx,
                                                  const _Float16* __restrict__ Wot,
                                                  float* __restrict__ Out) {
  constexpr int BK = 32;
  __shared__ alignas(16) _Float16 As[128 * BK];
  __shared__ alignas(16) _Float16 Bs[64 * BK];

  const int idx = ((blockIdx.x % 64) << 3) + (blockIdx.x / 64);
  const int bm = (idx >> 4) << 7;
  const int bn = (idx & 15) << 6;

  const int tid = threadIdx.x, lane = tid & 63, w = tid >> 6;
  const int i16 = lane & 15, g4 = lane >> 4;
  const int wr = w >> 1, wc = w & 1;

  f32x4 acc[4][2] = {};

  for (int kt = 0; kt < GK / BK; ++kt) {
#pragma unroll
    for (int u = 0; u < 2; ++u) {
      const int cb = ((w << 1) + u) << 6;
      const int c = cb + lane;
      const int r = c >> 2, sl = c & 3;
      const int m = bm + r;
      const int kcol = (kt << 5) + ((sl ^ (r & 3)) << 3);
      const int bb = m >> 11, ss = m & (NS - 1);
      const int hh = kcol >> 6, dd = kcol & 63;
      __builtin_amdgcn_global_load_lds(
          (gas_t)(const void*)(ctx + (((size_t)(bb * NH + hh) * NS + ss) << 6) + dd),
          (las_t)(void*)&As[cb << 3], 16, 0, 0);
    }
    {
      const int cb = w << 6;
      const int c = cb + lane;
      const int r = c >> 2, sl = c & 3;
      __builtin_amdgcn_global_load_lds(
          (gas_t)(const void*)(Wot + (size_t)(bn + r) * GK + (kt << 5) + ((sl ^ (r & 3)) << 3)),
          (las_t)(void*)&Bs[cb << 3], 16, 0, 0);
    }
    __syncthreads();

    f16x8 af[4], bf[2];
#pragma unroll
    for (int mi = 0; mi < 4; ++mi) {
      const int r = (wr << 6) + (mi << 4) + i16;
      af[mi] = *(const f16x8*)&As[(r << 5) + ((g4 ^ (r & 3)) << 3)];
    }
#pragma unroll
    for (int ni = 0; ni < 2; ++ni) {
      const int r = (wc << 5) + (ni << 4) + i16;
      bf[ni] = *(const f16x8*)&Bs[(r << 5) + ((g4 ^ (r & 3)) << 3)];
    }
#pragma unroll
    for (int mi = 0; mi < 4; ++mi)
#pragma unroll
      for (int ni = 0; ni < 2; ++ni)
        acc[mi][ni] = __builtin_amdgcn_mfma_f32_16x16x32_f16(af[mi], bf[ni], acc[mi][ni], 0, 0, 0);
    __syncthreads();
  }

#pragma unroll
  for (int mi = 0; mi < 4; ++mi)
#pragma unroll
    for (int ni = 0; ni < 2; ++ni)
#pragma unroll
      for (int j = 0; j < 4; ++j) {
        const int row = bm + (wr << 6) + (mi << 4) + (g4 << 2) + j;
        const int col = bn + (wc << 5) + (ni << 4) + i16;
        Out[(size_t)row * ND + col] = acc[mi][ni][j];
      }
}

extern "C" void kernel_launch(void* const* d_in, const int* in_sizes, int n_in,
                              void* d_out, int out_size, void* d_ws, size_t ws_size,
                              hipStream_t stream) {
  const float* q  = (const float*)d_in[0];
  const float* k  = (const float*)d_in[1];
  const float* v  = (const float*)d_in[2];
  const int*   vl = (const int*)d_in[3];
  const float* Wq = (const float*)d_in[4];
  const float* Wk = (const float*)d_in[5];
  const float* Wv = (const float*)d_in[6];
  const float* Wo = (const float*)d_in[7];

  _Float16* ws = (_Float16*)d_ws;
  _Float16* Qh  = ws;                        // 8 MB (becomes ctx in place)
  _Float16* Kh  = ws + 4194304;              // 8 MB
  _Float16* VhT = ws + 8388608;              // 8 MB, [b,h,d,s]
  _Float16* Wt  = ws + 12582912;             // 4 x 2 MB transposed fp16 weights

  prep_kernel<<<dim3(1024), dim3(256), 0, stream>>>(Wq, Wk, Wv, Wo, Wt);
  proj_kernel<<<dim3(768), dim3(256), 0, stream>>>(q, k, v, Wt, Qh, Kh, VhT);
  attn_kernel<<<dim3(NB * NH * (NS >> 6)), dim3(256), 0, stream>>>(Qh, Kh, VhT, vl);
  out_kernel<<<dim3(512), dim3(256), 0, stream>>>(Qh, Wt + 3145728, (float*)d_out);
}